// Round 7
// baseline (4589.930 us; speedup 1.0000x reference)
//
// v6: f32 replica, conv chain = sequential FMA over (kh, kw, ci) — Eigen gebp hypothesis.
// (r6 = mul+add same order: FAILED one-level -> naive-emitter ruled out.)
// Weights as packed sign masks (rounding-neutral: fmaf(x, +/-alpha, acc) unchanged).
#include <hip/hip_runtime.h>

#define OFF_PSUM   0UL            // 134217728 B  f32 psum[b][1024][32][32]
#define OFF_ALPHA  134217728UL    // 1024 B  (256 f32)
#define OFF_INV    134218752UL    // 4096 B
#define OFF_BT     134222848UL    // 4096 B
#define OFF_WSIGN  134226944UL    // 73728 B (9216 u64: [(co*4+g)*9+tap] -> 64 ci sign bits)

// ---------------- K0a: alpha (sequential scalar f32, XLA reduce replica) ----------------
__global__ __launch_bounds__(256) void k_alpha(const float* __restrict__ w,
                                               float* __restrict__ alpha) {
#pragma clang fp contract(off)
    int co = threadIdx.x;
    const float* p = w + (size_t)co * 2304;
    float s = 0.f;
    for (int k = 0; k < 2304; ++k) s = s + fabsf(p[k]);
    alpha[co] = s / 2304.0f;
}

// ---------------- K0b: pack weight sign bits: bit ci = 1 iff w < 0 ----------------
__global__ __launch_bounds__(256) void k_wsign(const float* __restrict__ w,
                                               unsigned long long* __restrict__ wsign) {
    int item = blockIdx.x * 256 + threadIdx.x;   // 9216
    if (item >= 9216) return;
    int co = item / 36, rem = item % 36;
    int g = rem / 9, tap = rem % 9;
    const float* wp = w + ((size_t)co * 256 + g * 64) * 9 + tap;
    unsigned long long m = 0ull;
#pragma unroll
    for (int ci = 0; ci < 64; ++ci)
        m |= (unsigned long long)(wp[ci * 9] < 0.f) << ci;
    wsign[item] = m;
}

// ---------------- K1: conv replica — sequential FMA chain (kh, kw, ci) per output ----------------
// block = (b, g, band): 2 output rows x 32 cols; 4 waves split co (64 each)
__global__ __launch_bounds__(256) void k_conv(const float* __restrict__ x,
                                              const unsigned long long* __restrict__ wsign,
                                              const float* __restrict__ alpha,
                                              float* __restrict__ psum) {
#pragma clang fp contract(off)
    __shared__ float xs[4][34][64];
    int bx = blockIdx.x;
    int band = bx & 15, g = (bx >> 4) & 3, b = bx >> 6;
    int t = threadIdx.x;

    const float* xg = x + (size_t)(b * 256 + g * 64) * 1024;
#pragma unroll
    for (int i = 0; i < 34; ++i) {              // 34*256 = 8704 slots
        int idx = i * 256 + t;
        int ci = idx & 63, col = (idx >> 6) % 34, row = idx / 2176;
        int gr = band * 2 + row - 1, gc = col - 1;
        float v = (gr >= 0 && gr < 32 && gc >= 0 && gc < 32)
                    ? xg[(size_t)ci * 1024 + gr * 32 + gc] : 0.f;
        xs[row][col][ci] = v;
    }
    __syncthreads();

    int wid = t >> 6, lane = t & 63;
    int r = lane >> 5, m = lane & 31;
    int h = band * 2 + r;

    for (int cog = 0; cog < 8; ++cog) {
        float acc[8];
#pragma unroll
        for (int j = 0; j < 8; ++j) acc[j] = 0.f;

#pragma unroll
        for (int kh = 0; kh < 3; ++kh)
#pragma unroll
            for (int kw = 0; kw < 3; ++kw) {
                int tap = kh * 3 + kw;
                float xv[64];
                const float* base = &xs[r + kh][m + kw][0];
#pragma unroll
                for (int q = 0; q < 16; ++q) {
                    float4 v4 = ((const float4*)base)[q];
                    xv[q * 4 + 0] = v4.x; xv[q * 4 + 1] = v4.y;
                    xv[q * 4 + 2] = v4.z; xv[q * 4 + 3] = v4.w;
                }
#pragma unroll
                for (int j = 0; j < 8; ++j) {
                    int co = wid * 64 + cog * 8 + j;             // wave-uniform
                    float av = alpha[co];                        // SGPR
                    unsigned long long mask = wsign[(co * 4 + g) * 9 + tap];
                    float a = acc[j];
#pragma unroll
                    for (int ci = 0; ci < 64; ++ci) {
                        float wv = ((mask >> ci) & 1ull) ? -av : av;  // w_bin exact
                        a = fmaf(xv[ci], wv, a);                 // Eigen gebp: fused chain
                    }
                    acc[j] = a;
                }
            }
#pragma unroll
        for (int j = 0; j < 8; ++j) {
            int co = wid * 64 + cog * 8 + j;
            psum[(((size_t)b * 1024 + g * 256 + co) * 32 + h) * 32 + m] = acc[j];
        }
    }
}

// ---------------- K2: BN stats replica — sequential f32 (b,h,w), two-pass var ----------------
__global__ __launch_bounds__(64) void k_stats(const float* __restrict__ psum,
                                              const float* __restrict__ gamma,
                                              const float* __restrict__ beta,
                                              float* __restrict__ invA,
                                              float* __restrict__ btA) {
#pragma clang fp contract(off)
    int ch = blockIdx.x * 64 + threadIdx.x;
    const float* base = psum + (size_t)ch * 1024;
    float s = 0.f;
    for (int b = 0; b < 32; ++b) {
        const float* pb = base + (size_t)b * 1048576;
#pragma unroll 8
        for (int i = 0; i < 1024; ++i) s = s + pb[i];
    }
    float mean = s / 32768.0f;
    float v = 0.f;
    for (int b = 0; b < 32; ++b) {
        const float* pb = base + (size_t)b * 1048576;
#pragma unroll 8
        for (int i = 0; i < 1024; ++i) {
            float d = pb[i] - mean;
            float dd = d * d;
            v = v + dd;
        }
    }
    float var = v / 32768.0f;
    float sq = sqrtf(var + 1e-5f);
    float inv = 1.0f / sq;
    inv = inv * gamma[ch];
    float mb = mean * inv;
    float bt = beta[ch] - mb;
    invA[ch] = inv; btA[ch] = bt;
}

// ---------------- K3: BN apply + sign + merge + literal qrelu ----------------
__global__ __launch_bounds__(256) void k_apply(const float* __restrict__ psum,
                                               const float* __restrict__ invA,
                                               const float* __restrict__ btA,
                                               float* __restrict__ out) {
#pragma clang fp contract(off)
    int idx = blockIdx.x * 256 + threadIdx.x;
    int w4 = (idx & 7) * 4;
    int hh = (idx >> 3) & 31;
    int co = (idx >> 8) & 255;
    int b  = idx >> 16;

    float s0 = 0.f, s1 = 0.f, s2 = 0.f, s3 = 0.f;
    for (int g = 0; g < 4; ++g) {
        int ch = g * 256 + co;
        const float4 p = *(const float4*)(psum + (((size_t)b * 1024 + ch) * 32 + hh) * 32 + w4);
        float iv = invA[ch], bt = btA[ch];
        float y0 = p.x * iv; y0 = y0 + bt;
        float y1 = p.y * iv; y1 = y1 + bt;
        float y2 = p.z * iv; y2 = y2 + bt;
        float y3 = p.w * iv; y3 = y3 + bt;
        s0 = s0 + ((y0 >= 0.f) ? 1.f : -1.f);
        s1 = s1 + ((y1 >= 0.f) ? 1.f : -1.f);
        s2 = s2 + ((y2 >= 0.f) ? 1.f : -1.f);
        s3 = s3 + ((y3 >= 0.f) ? 1.f : -1.f);
    }
    float4 q;
    {
        float u, rr, qq;
        u = s0 * 0.25f; u = fminf(fmaxf(u, 0.f), 1.f); rr = rintf(u * 15.f); qq = rr / 15.f; q.x = qq * 4.f;
        u = s1 * 0.25f; u = fminf(fmaxf(u, 0.f), 1.f); rr = rintf(u * 15.f); qq = rr / 15.f; q.y = qq * 4.f;
        u = s2 * 0.25f; u = fminf(fmaxf(u, 0.f), 1.f); rr = rintf(u * 15.f); qq = rr / 15.f; q.z = qq * 4.f;
        u = s3 * 0.25f; u = fminf(fmaxf(u, 0.f), 1.f); rr = rintf(u * 15.f); qq = rr / 15.f; q.w = qq * 4.f;
    }
    *(float4*)(out + (((size_t)b * 256 + co) * 32 + hh) * 32 + w4) = q;
}

extern "C" void kernel_launch(void* const* d_in, const int* in_sizes, int n_in,
                              void* d_out, int out_size, void* d_ws, size_t ws_size,
                              hipStream_t stream) {
    (void)in_sizes; (void)n_in; (void)out_size; (void)ws_size;
    const float* x     = (const float*)d_in[0];
    const float* w     = (const float*)d_in[1];
    const float* gamma = (const float*)d_in[2];
    const float* beta  = (const float*)d_in[3];
    float* out = (float*)d_out;
    char* ws = (char*)d_ws;
    float* psum  = (float*)(ws + OFF_PSUM);
    float* alpha = (float*)(ws + OFF_ALPHA);
    float* invA  = (float*)(ws + OFF_INV);
    float* btA   = (float*)(ws + OFF_BT);
    unsigned long long* wsign = (unsigned long long*)(ws + OFF_WSIGN);

    hipLaunchKernelGGL(k_alpha, dim3(1),    dim3(256), 0, stream, w, alpha);
    hipLaunchKernelGGL(k_wsign, dim3(36),   dim3(256), 0, stream, w, wsign);
    hipLaunchKernelGGL(k_conv,  dim3(2048), dim3(256), 0, stream, x, wsign, alpha, psum);
    hipLaunchKernelGGL(k_stats, dim3(16),   dim3(64),  0, stream, psum, gamma, beta, invA, btA);
    hipLaunchKernelGGL(k_apply, dim3(8192), dim3(256), 0, stream, psum, invA, btA, out);
}

// Round 8
// 2241.430 us; speedup vs baseline: 2.0478x; 2.0478x over previous
//
// v7: bit-exact replica (r7-validated chains), performance restructure.
// Invariant: per-output FP op sequence unchanged: conv = fmaf chain over (kh,kw,ci)
// with w_bin = +-alpha f32; alpha/BN chains sequential as r7. All changes are
// scheduling/layout only. wsa (+-alpha table) lives in d_out scratch (k_apply
// fully overwrites d_out afterwards).
#include <hip/hip_runtime.h>

#define OFF_PSUM   0UL            // 134217728 B  f32 psum[b][1024][32][32]
#define OFF_ALPHA  134217728UL    // 1024 B
#define OFF_INV    134218752UL    // 4096 B
#define OFF_BT     134222848UL    // 4096 B   (total 134.23 MB, proven fits)

// ---------------- K0a: alpha — LDS-staged, exact sequential chain ----------------
__global__ __launch_bounds__(256) void k_alpha(const float* __restrict__ w,
                                               float* __restrict__ alpha) {
#pragma clang fp contract(off)
    __shared__ float buf[2304];
    int co = blockIdx.x, t = threadIdx.x;
    const float* p = w + (size_t)co * 2304;
    for (int i = t; i < 2304; i += 256) buf[i] = p[i];
    __syncthreads();
    if (t == 0) {
        float s = 0.f;
#pragma unroll 8
        for (int k = 0; k < 2304; ++k) s = s + fabsf(buf[k]);
        alpha[co] = s / 2304.0f;
    }
}

// ---------------- K0b: build +-alpha table wsa[((co*4+g)*9+tap)*64+ci] ----------------
__global__ __launch_bounds__(256) void k_wsa(const float* __restrict__ w,
                                             const float* __restrict__ alpha,
                                             float* __restrict__ wsa) {
    int item = blockIdx.x * 256 + threadIdx.x;     // 589824 items
    int ci = item & 63;
    int idx = item >> 6;
    int tap = idx % 9; idx /= 9;
    int g = idx & 3, co = idx >> 2;
    float av = alpha[co];
    float wv = w[((size_t)co * 256 + g * 64 + ci) * 9 + tap];
    wsa[item] = (wv >= 0.f) ? av : -av;            // exact +-alpha (bit-same as r7)
}

// ---------------- K1: conv — same chain, 1 VALU/FMA via uniform (SGPR) weights ----------------
// block (b,g,band): 8 waves x 32 co; each thread: 1 px (2 rows x 32 cols per wave), acc[32]
__global__ __launch_bounds__(512, 2) void k_conv(const float* __restrict__ x,
                                                 const float* __restrict__ wsa,
                                                 float* __restrict__ psum) {
#pragma clang fp contract(off)
    __shared__ float xs[4][34][68];                // +4 pad: lane bank-stride 4 -> ~4-way
    int bx = blockIdx.x;
    int band = bx & 15, g = (bx >> 4) & 3, b = bx >> 6;
    int t = threadIdx.x;

    const float* xg = x + (size_t)(b * 256 + g * 64) * 1024;
#pragma unroll
    for (int i = 0; i < 17; ++i) {                 // 17*512 = 8704 elements
        int idx = i * 512 + t;
        int ci = idx & 63, col = (idx >> 6) % 34, row = idx / 2176;
        int gr = band * 2 + row - 1, gc = col - 1;
        float v = (gr >= 0 && gr < 32 && gc >= 0 && gc < 32)
                    ? xg[(size_t)ci * 1024 + gr * 32 + gc] : 0.f;
        xs[row][col][ci] = v;
    }
    __syncthreads();

    int wid = t >> 6, lane = t & 63;
    int r = lane >> 5, m = lane & 31;
    int h = band * 2 + r;
    int cobase = __builtin_amdgcn_readfirstlane(wid * 32);   // wave-uniform co base

    float acc[32];
#pragma unroll
    for (int j = 0; j < 32; ++j) acc[j] = 0.f;

#pragma unroll 1
    for (int kh = 0; kh < 3; ++kh)
#pragma unroll 1
        for (int kw = 0; kw < 3; ++kw) {
            int tap = kh * 3 + kw;
            float xv[64];
            const float* bp = &xs[r + kh][m + kw][0];
#pragma unroll
            for (int q = 0; q < 16; ++q) {
                float4 v4 = *(const float4*)(bp + q * 4);
                xv[q * 4 + 0] = v4.x; xv[q * 4 + 1] = v4.y;
                xv[q * 4 + 2] = v4.z; xv[q * 4 + 3] = v4.w;
            }
            const float* wbase = wsa + ((size_t)(cobase * 4 + g) * 9 + tap) * 64;
#pragma unroll
            for (int j = 0; j < 32; ++j) {         // wr uniform -> s_load; fma v,v,s,v
                const float* wr = wbase + (size_t)j * 2304;
                float s = acc[j];
#pragma unroll
                for (int ci = 0; ci < 64; ++ci)
                    s = fmaf(xv[ci], wr[ci], s);   // chain order (kh,kw,ci) preserved
                acc[j] = s;
            }
        }

#pragma unroll
    for (int j = 0; j < 32; ++j) {
        int co = cobase + j;
        psum[(((size_t)b * 1024 + g * 256 + co) * 32 + h) * 32 + m] = acc[j];
    }
}

// ---------------- K2: BN stats — exact sequential chains, LDS double-buffer ----------------
__global__ __launch_bounds__(256) void k_stats(const float* __restrict__ psum,
                                               const float* __restrict__ gamma,
                                               const float* __restrict__ beta,
                                               float* __restrict__ invA,
                                               float* __restrict__ btA) {
#pragma clang fp contract(off)
    __shared__ float buf[2][1024];
    __shared__ float res[1];
    int ch = blockIdx.x, t = threadIdx.x;
    const float* base = psum + (size_t)ch * 1024;

    float4 pre = *(const float4*)(base + t * 4);
    *(float4*)&buf[0][t * 4] = pre;
    __syncthreads();
    float s = 0.f;
    for (int b = 0; b < 32; ++b) {
        if (b + 1 < 32) pre = *(const float4*)(base + (size_t)(b + 1) * 1048576 + t * 4);
        if (t == 0) {
            const float* pb = buf[b & 1];
#pragma unroll 8
            for (int i = 0; i < 1024; ++i) s = s + pb[i];   // exact (b,h,w) chain
        }
        __syncthreads();
        if (b + 1 < 32) *(float4*)&buf[(b + 1) & 1][t * 4] = pre;
        __syncthreads();
    }
    if (t == 0) res[0] = s / 32768.0f;
    __syncthreads();
    float mean = res[0];

    pre = *(const float4*)(base + t * 4);
    *(float4*)&buf[0][t * 4] = pre;
    __syncthreads();
    float v = 0.f;
    for (int b = 0; b < 32; ++b) {
        if (b + 1 < 32) pre = *(const float4*)(base + (size_t)(b + 1) * 1048576 + t * 4);
        if (t == 0) {
            const float* pb = buf[b & 1];
#pragma unroll 8
            for (int i = 0; i < 1024; ++i) {
                float d = pb[i] - mean;
                float dd = d * d;                  // separate roundings (no fma)
                v = v + dd;
            }
        }
        __syncthreads();
        if (b + 1 < 32) *(float4*)&buf[(b + 1) & 1][t * 4] = pre;
        __syncthreads();
    }
    if (t == 0) {
        float var = v / 32768.0f;
        float sq = sqrtf(var + 1e-5f);
        float inv = 1.0f / sq;
        inv = inv * gamma[ch];
        float mb = mean * inv;
        invA[ch] = inv;
        btA[ch] = beta[ch] - mb;
    }
}

// ---------------- K3: BN apply + sign + merge + literal qrelu (unchanged, passed) ----------------
__global__ __launch_bounds__(256) void k_apply(const float* __restrict__ psum,
                                               const float* __restrict__ invA,
                                               const float* __restrict__ btA,
                                               float* __restrict__ out) {
#pragma clang fp contract(off)
    int idx = blockIdx.x * 256 + threadIdx.x;
    int w4 = (idx & 7) * 4;
    int hh = (idx >> 3) & 31;
    int co = (idx >> 8) & 255;
    int b  = idx >> 16;

    float s0 = 0.f, s1 = 0.f, s2 = 0.f, s3 = 0.f;
    for (int g = 0; g < 4; ++g) {
        int ch = g * 256 + co;
        const float4 p = *(const float4*)(psum + (((size_t)b * 1024 + ch) * 32 + hh) * 32 + w4);
        float iv = invA[ch], bt = btA[ch];
        float y0 = p.x * iv; y0 = y0 + bt;
        float y1 = p.y * iv; y1 = y1 + bt;
        float y2 = p.z * iv; y2 = y2 + bt;
        float y3 = p.w * iv; y3 = y3 + bt;
        s0 = s0 + ((y0 >= 0.f) ? 1.f : -1.f);
        s1 = s1 + ((y1 >= 0.f) ? 1.f : -1.f);
        s2 = s2 + ((y2 >= 0.f) ? 1.f : -1.f);
        s3 = s3 + ((y3 >= 0.f) ? 1.f : -1.f);
    }
    float4 q;
    {
        float u, rr, qq;
        u = s0 * 0.25f; u = fminf(fmaxf(u, 0.f), 1.f); rr = rintf(u * 15.f); qq = rr / 15.f; q.x = qq * 4.f;
        u = s1 * 0.25f; u = fminf(fmaxf(u, 0.f), 1.f); rr = rintf(u * 15.f); qq = rr / 15.f; q.y = qq * 4.f;
        u = s2 * 0.25f; u = fminf(fmaxf(u, 0.f), 1.f); rr = rintf(u * 15.f); qq = rr / 15.f; q.z = qq * 4.f;
        u = s3 * 0.25f; u = fminf(fmaxf(u, 0.f), 1.f); rr = rintf(u * 15.f); qq = rr / 15.f; q.w = qq * 4.f;
    }
    *(float4*)(out + (((size_t)b * 256 + co) * 32 + hh) * 32 + w4) = q;
}

extern "C" void kernel_launch(void* const* d_in, const int* in_sizes, int n_in,
                              void* d_out, int out_size, void* d_ws, size_t ws_size,
                              hipStream_t stream) {
    (void)in_sizes; (void)n_in; (void)out_size; (void)ws_size;
    const float* x     = (const float*)d_in[0];
    const float* w     = (const float*)d_in[1];
    const float* gamma = (const float*)d_in[2];
    const float* beta  = (const float*)d_in[3];
    float* out = (float*)d_out;
    char* ws = (char*)d_ws;
    float* psum  = (float*)(ws + OFF_PSUM);
    float* alpha = (float*)(ws + OFF_ALPHA);
    float* invA  = (float*)(ws + OFF_INV);
    float* btA   = (float*)(ws + OFF_BT);
    float* wsa   = out;                 // 2.36 MB scratch in d_out; k_apply overwrites later

    hipLaunchKernelGGL(k_alpha, dim3(256),  dim3(256), 0, stream, w, alpha);
    hipLaunchKernelGGL(k_wsa,   dim3(2304), dim3(256), 0, stream, w, alpha, wsa);
    hipLaunchKernelGGL(k_conv,  dim3(2048), dim3(512), 0, stream, x, wsa, psum);
    hipLaunchKernelGGL(k_stats, dim3(1024), dim3(256), 0, stream, psum, gamma, beta, invA, btA);
    hipLaunchKernelGGL(k_apply, dim3(8192), dim3(256), 0, stream, psum, invA, btA, out);
}

// Round 9
// 1534.686 us; speedup vs baseline: 2.9908x; 1.4605x over previous
//
// v8: bit-exact replica; k_conv loop-interchange (ci outer, co inner — per-acc chain
// order (kh,kw,ci) unchanged), weights via wave-uniform SGPR loads from transposed
// wsaT[g][tap][ci][co]; k_stats chain reads b128. All FP sequences identical to r7/r8.
#include <hip/hip_runtime.h>

#define OFF_PSUM   0UL            // 134217728 B  f32 psum[b][1024][32][32]
#define OFF_ALPHA  134217728UL    // 1024 B
#define OFF_INV    134218752UL    // 4096 B
#define OFF_BT     134222848UL    // 4096 B   (total 134.23 MB, proven fits)

// ---------------- K0a: alpha — LDS-staged, exact sequential chain ----------------
__global__ __launch_bounds__(256) void k_alpha(const float* __restrict__ w,
                                               float* __restrict__ alpha) {
#pragma clang fp contract(off)
    __shared__ float buf[2304];
    int co = blockIdx.x, t = threadIdx.x;
    const float* p = w + (size_t)co * 2304;
    for (int i = t; i < 2304; i += 256) buf[i] = p[i];
    __syncthreads();
    if (t == 0) {
        float s = 0.f;
#pragma unroll 16
        for (int k = 0; k < 2304; ++k) s = s + fabsf(buf[k]);
        alpha[co] = s / 2304.0f;
    }
}

// ---------------- K0b: transposed +-alpha table wsaT[((g*9+tap)*64+ci)*256+co] ----------------
__global__ __launch_bounds__(256) void k_wsaT(const float* __restrict__ w,
                                              const float* __restrict__ alpha,
                                              float* __restrict__ wsaT) {
    int item = blockIdx.x * 256 + threadIdx.x;     // 589824 items
    int co = item & 255;
    int rest = item >> 8;                           // 0..2303
    int ci = rest & 63;
    int t9 = rest >> 6;                             // 0..35
    int tap = t9 % 9, g = t9 / 9;
    float av = alpha[co];
    float wv = w[((size_t)co * 256 + g * 64 + ci) * 9 + tap];
    wsaT[item] = (wv >= 0.f) ? av : -av;           // exact +-alpha, bit-same as r7/r8
}

// ---------------- K1: conv — ci-outer/co-inner, SGPR weights, 1 VALU per FMA ----------------
// block (b,g,band): 8 waves x 32 co; thread = 1 px; acc[32]; xv[64] register-resident
__global__ __launch_bounds__(512, 2) void k_conv(const float* __restrict__ x,
                                                 const float* __restrict__ wsaT,
                                                 float* __restrict__ psum) {
#pragma clang fp contract(off)
    __shared__ float xs[4][34][68];
    int bx = blockIdx.x;
    int band = bx & 15, g = (bx >> 4) & 3, b = bx >> 6;
    int t = threadIdx.x;

    const float* xg = x + (size_t)(b * 256 + g * 64) * 1024;
#pragma unroll
    for (int i = 0; i < 17; ++i) {                 // 17*512 = 8704 elements
        int idx = i * 512 + t;
        int ci = idx & 63, col = (idx >> 6) % 34, row = idx / 2176;
        int gr = band * 2 + row - 1, gc = col - 1;
        float v = (gr >= 0 && gr < 32 && gc >= 0 && gc < 32)
                    ? xg[(size_t)ci * 1024 + gr * 32 + gc] : 0.f;
        xs[row][col][ci] = v;
    }
    __syncthreads();

    int wid = t >> 6, lane = t & 63;
    int r = lane >> 5, m = lane & 31;
    int h = band * 2 + r;
    int cobase = __builtin_amdgcn_readfirstlane(wid * 32);   // wave-uniform

    float acc[32];
#pragma unroll
    for (int j = 0; j < 32; ++j) acc[j] = 0.f;

#pragma unroll 1
    for (int kh = 0; kh < 3; ++kh)
#pragma unroll 1
        for (int kw = 0; kw < 3; ++kw) {
            int tap = kh * 3 + kw;
            float xv[64];
            const float* bp = &xs[r + kh][m + kw][0];
#pragma unroll
            for (int q = 0; q < 16; ++q) {
                float4 v4 = *(const float4*)(bp + q * 4);
                xv[q * 4 + 0] = v4.x; xv[q * 4 + 1] = v4.y;
                xv[q * 4 + 2] = v4.z; xv[q * 4 + 3] = v4.w;
            }
            // wave-uniform weight row base for this (g,tap): wsaT[...][ci][co]
            const float* wt = wsaT + (((size_t)(g * 9 + tap) * 64) << 8) + cobase;
#pragma unroll
            for (int ci = 0; ci < 64; ++ci) {      // per-acc chain order preserved
                const float* wr = wt + (ci << 8);  // uniform -> s_load_dwordx16
#pragma unroll
                for (int j = 0; j < 32; ++j)
                    acc[j] = fmaf(xv[ci], wr[j], acc[j]);
            }
        }

#pragma unroll
    for (int j = 0; j < 32; ++j) {
        int co = cobase + j;
        psum[(((size_t)b * 1024 + g * 256 + co) * 32 + h) * 32 + m] = acc[j];
    }
}

// ---------------- K2: BN stats — exact sequential chains, b128 chain reads ----------------
__global__ __launch_bounds__(256) void k_stats(const float* __restrict__ psum,
                                               const float* __restrict__ gamma,
                                               const float* __restrict__ beta,
                                               float* __restrict__ invA,
                                               float* __restrict__ btA) {
#pragma clang fp contract(off)
    __shared__ float buf[2][1024];
    __shared__ float res[1];
    int ch = blockIdx.x, t = threadIdx.x;
    const float* base = psum + (size_t)ch * 1024;

    float4 pre = *(const float4*)(base + t * 4);
    *(float4*)&buf[0][t * 4] = pre;
    __syncthreads();
    float s = 0.f;
    for (int b = 0; b < 32; ++b) {
        if (b + 1 < 32) pre = *(const float4*)(base + (size_t)(b + 1) * 1048576 + t * 4);
        if (t == 0) {
            const float* pb = buf[b & 1];
#pragma unroll 16
            for (int i4 = 0; i4 < 256; ++i4) {     // exact (h,w) order, b128 reads
                float4 v = *(const float4*)(pb + i4 * 4);
                s = s + v.x; s = s + v.y; s = s + v.z; s = s + v.w;
            }
        }
        __syncthreads();
        if (b + 1 < 32) *(float4*)&buf[(b + 1) & 1][t * 4] = pre;
        __syncthreads();
    }
    if (t == 0) res[0] = s / 32768.0f;
    __syncthreads();
    float mean = res[0];

    pre = *(const float4*)(base + t * 4);
    *(float4*)&buf[0][t * 4] = pre;
    __syncthreads();
    float v = 0.f;
    for (int b = 0; b < 32; ++b) {
        if (b + 1 < 32) pre = *(const float4*)(base + (size_t)(b + 1) * 1048576 + t * 4);
        if (t == 0) {
            const float* pb = buf[b & 1];
#pragma unroll 16
            for (int i4 = 0; i4 < 256; ++i4) {
                float4 p4 = *(const float4*)(pb + i4 * 4);
                float d0 = p4.x - mean; float q0 = d0 * d0; v = v + q0;
                float d1 = p4.y - mean; float q1 = d1 * d1; v = v + q1;
                float d2 = p4.z - mean; float q2 = d2 * d2; v = v + q2;
                float d3 = p4.w - mean; float q3 = d3 * d3; v = v + q3;
            }
        }
        __syncthreads();
        if (b + 1 < 32) *(float4*)&buf[(b + 1) & 1][t * 4] = pre;
        __syncthreads();
    }
    if (t == 0) {
        float var = v / 32768.0f;
        float sq = sqrtf(var + 1e-5f);
        float inv = 1.0f / sq;
        inv = inv * gamma[ch];
        float mb = mean * inv;
        invA[ch] = inv;
        btA[ch] = beta[ch] - mb;
    }
}

// ---------------- K3: BN apply + sign + merge + literal qrelu (unchanged, passed) ----------------
__global__ __launch_bounds__(256) void k_apply(const float* __restrict__ psum,
                                               const float* __restrict__ invA,
                                               const float* __restrict__ btA,
                                               float* __restrict__ out) {
#pragma clang fp contract(off)
    int idx = blockIdx.x * 256 + threadIdx.x;
    int w4 = (idx & 7) * 4;
    int hh = (idx >> 3) & 31;
    int co = (idx >> 8) & 255;
    int b  = idx >> 16;

    float s0 = 0.f, s1 = 0.f, s2 = 0.f, s3 = 0.f;
    for (int g = 0; g < 4; ++g) {
        int ch = g * 256 + co;
        const float4 p = *(const float4*)(psum + (((size_t)b * 1024 + ch) * 32 + hh) * 32 + w4);
        float iv = invA[ch], bt = btA[ch];
        float y0 = p.x * iv; y0 = y0 + bt;
        float y1 = p.y * iv; y1 = y1 + bt;
        float y2 = p.z * iv; y2 = y2 + bt;
        float y3 = p.w * iv; y3 = y3 + bt;
        s0 = s0 + ((y0 >= 0.f) ? 1.f : -1.f);
        s1 = s1 + ((y1 >= 0.f) ? 1.f : -1.f);
        s2 = s2 + ((y2 >= 0.f) ? 1.f : -1.f);
        s3 = s3 + ((y3 >= 0.f) ? 1.f : -1.f);
    }
    float4 q;
    {
        float u, rr, qq;
        u = s0 * 0.25f; u = fminf(fmaxf(u, 0.f), 1.f); rr = rintf(u * 15.f); qq = rr / 15.f; q.x = qq * 4.f;
        u = s1 * 0.25f; u = fminf(fmaxf(u, 0.f), 1.f); rr = rintf(u * 15.f); qq = rr / 15.f; q.y = qq * 4.f;
        u = s2 * 0.25f; u = fminf(fmaxf(u, 0.f), 1.f); rr = rintf(u * 15.f); qq = rr / 15.f; q.z = qq * 4.f;
        u = s3 * 0.25f; u = fminf(fmaxf(u, 0.f), 1.f); rr = rintf(u * 15.f); qq = rr / 15.f; q.w = qq * 4.f;
    }
    *(float4*)(out + (((size_t)b * 256 + co) * 32 + hh) * 32 + w4) = q;
}

extern "C" void kernel_launch(void* const* d_in, const int* in_sizes, int n_in,
                              void* d_out, int out_size, void* d_ws, size_t ws_size,
                              hipStream_t stream) {
    (void)in_sizes; (void)n_in; (void)out_size; (void)ws_size;
    const float* x     = (const float*)d_in[0];
    const float* w     = (const float*)d_in[1];
    const float* gamma = (const float*)d_in[2];
    const float* beta  = (const float*)d_in[3];
    float* out = (float*)d_out;
    char* ws = (char*)d_ws;
    float* psum  = (float*)(ws + OFF_PSUM);
    float* alpha = (float*)(ws + OFF_ALPHA);
    float* invA  = (float*)(ws + OFF_INV);
    float* btA   = (float*)(ws + OFF_BT);
    float* wsaT  = out;                 // 2.36 MB scratch in d_out; k_apply overwrites later

    hipLaunchKernelGGL(k_alpha, dim3(256),  dim3(256), 0, stream, w, alpha);
    hipLaunchKernelGGL(k_wsaT,  dim3(2304), dim3(256), 0, stream, w, alpha, wsaT);
    hipLaunchKernelGGL(k_conv,  dim3(2048), dim3(512), 0, stream, x, wsaT, psum);
    hipLaunchKernelGGL(k_stats, dim3(1024), dim3(256), 0, stream, psum, gamma, beta, invA, btA);
    hipLaunchKernelGGL(k_apply, dim3(8192), dim3(256), 0, stream, psum, invA, btA, out);
}